// Round 1
// baseline (452.219 us; speedup 1.0000x reference)
//
#include <hip/hip_runtime.h>
#include <math.h>

#define T 8
#define N 1024
#define D 128

constexpr float SCALE = 0.08838834764831845f; // 1/sqrt(128)

// ---------------- Kernel 1: S[t] = mask(X_t X_t^T * scale) ----------------
// 64x64 tile per block, K=128 in two 64-chunks. 256 threads, 4x4 micro-tile.
__global__ __launch_bounds__(256) void gemm1_mask(const float* __restrict__ X,
                                                  const int* __restrict__ adj,
                                                  float* __restrict__ S) {
    const int t  = blockIdx.z;
    const int i0 = blockIdx.y * 64;
    const int j0 = blockIdx.x * 64;
    const float* Xt = X + (size_t)t * N * D;

    __shared__ float As[64 * 68];   // row pad 68 floats (272B, 16B aligned)
    __shared__ float Bs[64 * 68];

    const int tid = threadIdx.x;
    const int tx = tid & 15, ty = tid >> 4;

    float acc[4][4];
    #pragma unroll
    for (int r = 0; r < 4; ++r)
        #pragma unroll
        for (int c = 0; c < 4; ++c) acc[r][c] = 0.f;

    for (int kc = 0; kc < D; kc += 64) {
        #pragma unroll
        for (int p = 0; p < 4; ++p) {
            int idx = tid + p * 256;           // 0..1023
            int r = idx >> 4, c4 = (idx & 15) * 4;
            *(float4*)(As + r * 68 + c4) = *(const float4*)(Xt + (size_t)(i0 + r) * D + kc + c4);
            *(float4*)(Bs + r * 68 + c4) = *(const float4*)(Xt + (size_t)(j0 + r) * D + kc + c4);
        }
        __syncthreads();
        #pragma unroll
        for (int k4 = 0; k4 < 16; ++k4) {
            float4 a4[4], b4[4];
            #pragma unroll
            for (int r = 0; r < 4; ++r) a4[r] = *(const float4*)(As + (ty * 4 + r) * 68 + k4 * 4);
            #pragma unroll
            for (int c = 0; c < 4; ++c) b4[c] = *(const float4*)(Bs + (tx * 4 + c) * 68 + k4 * 4);
            #pragma unroll
            for (int r = 0; r < 4; ++r)
                #pragma unroll
                for (int c = 0; c < 4; ++c)
                    acc[r][c] += a4[r].x * b4[c].x + a4[r].y * b4[c].y
                               + a4[r].z * b4[c].z + a4[r].w * b4[c].w;
        }
        __syncthreads();
    }

    float* St = S + (size_t)t * N * N;
    #pragma unroll
    for (int r = 0; r < 4; ++r) {
        int i = i0 + ty * 4 + r;
        int jb = j0 + tx * 4;
        int4 m = *(const int4*)(adj + (size_t)i * N + jb);
        float4 v;
        v.x = m.x != 0 ? acc[r][0] * SCALE : -1e12f;
        v.y = m.y != 0 ? acc[r][1] * SCALE : -1e12f;
        v.z = m.z != 0 ? acc[r][2] * SCALE : -1e12f;
        v.w = m.w != 0 ? acc[r][3] * SCALE : -1e12f;
        *(float4*)(St + (size_t)i * N + jb) = v;
    }
}

// ---------------- Kernel 2: row softmax over S (8192 rows x 1024) ----------------
// One wave per row; 16 floats per lane held in registers.
__global__ __launch_bounds__(256) void softmax_rows(float* __restrict__ S) {
    const int row  = blockIdx.x * 4 + (threadIdx.x >> 6);
    const int lane = threadIdx.x & 63;
    float4* pv = (float4*)(S + (size_t)row * N);

    float4 v[4];
    float mx = -INFINITY;
    #pragma unroll
    for (int q = 0; q < 4; ++q) {
        v[q] = pv[q * 64 + lane];
        mx = fmaxf(mx, fmaxf(fmaxf(v[q].x, v[q].y), fmaxf(v[q].z, v[q].w)));
    }
    #pragma unroll
    for (int off = 32; off > 0; off >>= 1) mx = fmaxf(mx, __shfl_xor(mx, off));

    float sum = 0.f;
    #pragma unroll
    for (int q = 0; q < 4; ++q) {
        v[q].x = __expf(v[q].x - mx); v[q].y = __expf(v[q].y - mx);
        v[q].z = __expf(v[q].z - mx); v[q].w = __expf(v[q].w - mx);
        sum += v[q].x + v[q].y + v[q].z + v[q].w;
    }
    #pragma unroll
    for (int off = 32; off > 0; off >>= 1) sum += __shfl_xor(sum, off);
    const float inv = 1.f / sum;

    #pragma unroll
    for (int q = 0; q < 4; ++q) {
        v[q].x *= inv; v[q].y *= inv; v[q].z *= inv; v[q].w *= inv;
        pv[q * 64 + lane] = v[q];
    }
}

// ---------------- Kernel 3: NF[t] = P[t] (1024x1024) * X_t (1024x128) ----------------
// Block: 32 rows x 128 cols; 256 threads; 4x4 micro-tile; K-chunks of 32.
__global__ __launch_bounds__(256) void gemm2(const float* __restrict__ P,
                                             const float* __restrict__ X,
                                             float* __restrict__ NF) {
    const int t  = blockIdx.y;
    const int i0 = blockIdx.x * 32;
    const float* At = P + (size_t)t * N * N;
    const float* Xt = X + (size_t)t * N * D;

    __shared__ float Ps[32 * 36];
    __shared__ float Xs[32 * 132];

    const int tid = threadIdx.x;
    const int tx = tid & 31, ty = tid >> 5;   // tx: col group (0..31), ty: row group (0..7)

    float acc[4][4];
    #pragma unroll
    for (int r = 0; r < 4; ++r)
        #pragma unroll
        for (int c = 0; c < 4; ++c) acc[r][c] = 0.f;

    for (int kc = 0; kc < N; kc += 32) {
        {
            int r = tid >> 3, c4 = (tid & 7) * 4;
            *(float4*)(Ps + r * 36 + c4) = *(const float4*)(At + (size_t)(i0 + r) * N + kc + c4);
        }
        #pragma unroll
        for (int p = 0; p < 4; ++p) {
            int idx = tid + p * 256;          // 0..1023
            int r = idx >> 5, c4 = (idx & 31) * 4;
            *(float4*)(Xs + r * 132 + c4) = *(const float4*)(Xt + (size_t)(kc + r) * D + c4);
        }
        __syncthreads();
        #pragma unroll
        for (int k4 = 0; k4 < 8; ++k4) {
            float av[4][4];
            #pragma unroll
            for (int r = 0; r < 4; ++r) {
                float4 a = *(const float4*)(Ps + (ty * 4 + r) * 36 + k4 * 4);
                av[r][0] = a.x; av[r][1] = a.y; av[r][2] = a.z; av[r][3] = a.w;
            }
            #pragma unroll
            for (int j = 0; j < 4; ++j) {
                float4 x4 = *(const float4*)(Xs + (k4 * 4 + j) * 132 + tx * 4);
                #pragma unroll
                for (int r = 0; r < 4; ++r) {
                    acc[r][0] += av[r][j] * x4.x;
                    acc[r][1] += av[r][j] * x4.y;
                    acc[r][2] += av[r][j] * x4.z;
                    acc[r][3] += av[r][j] * x4.w;
                }
            }
        }
        __syncthreads();
    }

    float* NFt = NF + (size_t)t * N * D;
    #pragma unroll
    for (int r = 0; r < 4; ++r) {
        int i = i0 + ty * 4 + r;
        float4 v = make_float4(acc[r][0], acc[r][1], acc[r][2], acc[r][3]);
        *(float4*)(NFt + (size_t)i * D + tx * 4) = v;
    }
}

// ---------------- Kernel 4: SW[j,a,b] = sigmoid(scale * dot(NF[a,j,:], NF[b,j,:])) ----------------
__global__ __launch_bounds__(64) void temporal(const float* __restrict__ NF,
                                               float* __restrict__ SW) {
    const int j = blockIdx.x;
    __shared__ float F[T][D];
    const int tid = threadIdx.x;
    #pragma unroll
    for (int p = 0; p < 4; ++p) {
        int idx = tid + p * 64;               // 0..255 float4 slots
        int a = idx >> 5, c4 = (idx & 31) * 4;
        *(float4*)(&F[a][c4]) = *(const float4*)(NF + ((size_t)a * N + j) * D + c4);
    }
    __syncthreads();
    const int a = tid >> 3, b = tid & 7;
    float s = 0.f;
    #pragma unroll
    for (int d4 = 0; d4 < 32; ++d4) {
        float4 fa = *(const float4*)(&F[a][d4 * 4]);
        float4 fb = *(const float4*)(&F[b][d4 * 4]);
        s += fa.x * fb.x + fa.y * fb.y + fa.z * fb.z + fa.w * fb.w;
    }
    s *= SCALE;
    SW[(size_t)j * 64 + tid] = 1.f / (1.f + __expf(-s));
}

// ---------------- Kernel 5: out[b*N+j, a*N+i] = SW[j,a,b] (broadcast over i) ----------------
__global__ __launch_bounds__(256) void expand(const float* __restrict__ SW,
                                              float* __restrict__ out) {
    const int row = blockIdx.x;               // 0..8191 = b*N + j
    const int b = row >> 10, j = row & 1023;
    const int tid = threadIdx.x;
    float4* orow = (float4*)(out + (size_t)row * (T * N));
    #pragma unroll
    for (int a = 0; a < T; ++a) {
        float w = SW[(size_t)j * 64 + a * 8 + b];
        orow[a * 256 + tid] = make_float4(w, w, w, w);
    }
}

extern "C" void kernel_launch(void* const* d_in, const int* in_sizes, int n_in,
                              void* d_out, int out_size, void* d_ws, size_t ws_size,
                              hipStream_t stream) {
    const float* X   = (const float*)d_in[0];   // [T,N,D] fp32
    const int*   adj = (const int*)d_in[1];     // [N,N] int32
    float* out = (float*)d_out;                 // [T*N, T*N] fp32

    float* S  = (float*)d_ws;                   // T*N*N floats (33.5 MB)
    float* NF = S + (size_t)T * N * N;          // T*N*D floats (4 MB)
    float* SW = NF + (size_t)T * N * D;         // N*T*T floats (256 KB)

    gemm1_mask<<<dim3(16, 16, T), 256, 0, stream>>>(X, adj, S);
    softmax_rows<<<dim3(T * N / 4), 256, 0, stream>>>(S);
    gemm2<<<dim3(N / 32, T), 256, 0, stream>>>(S, X, NF);
    temporal<<<dim3(N), 64, 0, stream>>>(NF, SW);
    expand<<<dim3(T * N), 256, 0, stream>>>(SW, out);
}

// Round 2
// 370.383 us; speedup vs baseline: 1.2210x; 1.2210x over previous
//
#include <hip/hip_runtime.h>
#include <hip/hip_bf16.h>
#include <math.h>

#define T 8
#define N 1024
#define D 128

constexpr float SCALE = 0.08838834764831845f; // 1/sqrt(128)

typedef __attribute__((ext_vector_type(8))) short short8;   // 8 bf16 (4 VGPRs)
typedef __attribute__((ext_vector_type(4))) float floatx4;  // MFMA acc

// ---------------- Kernel 0: X fp32 -> bf16 ----------------
__global__ __launch_bounds__(256) void convert_bf16(const float* __restrict__ X,
                                                    ushort* __restrict__ XB) {
    int idx = blockIdx.x * 256 + threadIdx.x;   // float4 index
    float4 v = ((const float4*)X)[idx];
    ushort4 o;
    __hip_bfloat16 h;
    h = __float2bfloat16(v.x); o.x = *(ushort*)&h;
    h = __float2bfloat16(v.y); o.y = *(ushort*)&h;
    h = __float2bfloat16(v.z); o.z = *(ushort*)&h;
    h = __float2bfloat16(v.w); o.w = *(ushort*)&h;
    ((ushort4*)XB)[idx] = o;
}

// ---------------- Kernel 1: S[t] = mask(X_t X_t^T * scale), bf16 MFMA ----------------
// One wave = one 64x64 output tile. 4x4 grid of 16x16x32 MFMAs, K=128 in 4 chunks.
// No LDS: fragments loaded directly from L2-resident XB rows.
// A-frag: lane reads X[i0+16r+(lane&15)][k0 + (lane>>4)*8 .. +8]  (16B)
// B-frag: lane reads X[j0+16c+(lane&15)][k0 + (lane>>4)*8 .. +8]  (B^T pattern)
// C/D:    col = lane&15, row = (lane>>4)*4 + reg   [m89/m91 verified]
__global__ __launch_bounds__(256) void gemm1_mfma(const ushort* __restrict__ XB,
                                                  const int* __restrict__ adj,
                                                  float* __restrict__ S) {
    const int wid  = threadIdx.x >> 6;
    const int lane = threadIdx.x & 63;
    const int gw   = blockIdx.x * 4 + wid;      // 0..2047
    const int t    = gw >> 8;
    const int tile = gw & 255;
    const int i0 = (tile >> 4) * 64;
    const int j0 = (tile & 15) * 64;
    const int m = lane & 15, quad = lane >> 4;

    const ushort* Xt = XB + (size_t)t * N * D;

    const ushort* pa[4];
    const ushort* pb[4];
    #pragma unroll
    for (int r = 0; r < 4; ++r) {
        pa[r] = Xt + (size_t)(i0 + 16 * r + m) * D + quad * 8;
        pb[r] = Xt + (size_t)(j0 + 16 * r + m) * D + quad * 8;
    }

    floatx4 acc[4][4] = {};
    #pragma unroll
    for (int kq = 0; kq < 4; ++kq) {            // k0 = kq*32
        short8 a[4], b[4];
        #pragma unroll
        for (int r = 0; r < 4; ++r) {
            a[r] = *(const short8*)(pa[r] + kq * 32);
            b[r] = *(const short8*)(pb[r] + kq * 32);
        }
        #pragma unroll
        for (int r = 0; r < 4; ++r)
            #pragma unroll
            for (int c = 0; c < 4; ++c)
                acc[r][c] = __builtin_amdgcn_mfma_f32_16x16x32_bf16(a[r], b[c], acc[r][c], 0, 0, 0);
    }

    float* St = S + (size_t)t * N * N;
    #pragma unroll
    for (int r = 0; r < 4; ++r) {
        #pragma unroll
        for (int q = 0; q < 4; ++q) {
            const int i = i0 + 16 * r + quad * 4 + q;
            const int* arow = adj + (size_t)i * N;
            float* srow = St + (size_t)i * N;
            #pragma unroll
            for (int c = 0; c < 4; ++c) {
                const int j = j0 + 16 * c + m;
                float v = acc[r][c][q] * SCALE;
                srow[j] = (arow[j] != 0) ? v : -1e12f;
            }
        }
    }
}

// ---------------- Kernel 2: row softmax over S (8192 rows x 1024) ----------------
__global__ __launch_bounds__(256) void softmax_rows(float* __restrict__ S) {
    const int row  = blockIdx.x * 4 + (threadIdx.x >> 6);
    const int lane = threadIdx.x & 63;
    float4* pv = (float4*)(S + (size_t)row * N);

    float4 v[4];
    float mx = -INFINITY;
    #pragma unroll
    for (int q = 0; q < 4; ++q) {
        v[q] = pv[q * 64 + lane];
        mx = fmaxf(mx, fmaxf(fmaxf(v[q].x, v[q].y), fmaxf(v[q].z, v[q].w)));
    }
    #pragma unroll
    for (int off = 32; off > 0; off >>= 1) mx = fmaxf(mx, __shfl_xor(mx, off));

    float sum = 0.f;
    #pragma unroll
    for (int q = 0; q < 4; ++q) {
        v[q].x = __expf(v[q].x - mx); v[q].y = __expf(v[q].y - mx);
        v[q].z = __expf(v[q].z - mx); v[q].w = __expf(v[q].w - mx);
        sum += v[q].x + v[q].y + v[q].z + v[q].w;
    }
    #pragma unroll
    for (int off = 32; off > 0; off >>= 1) sum += __shfl_xor(sum, off);
    const float inv = 1.f / sum;

    #pragma unroll
    for (int q = 0; q < 4; ++q) {
        v[q].x *= inv; v[q].y *= inv; v[q].z *= inv; v[q].w *= inv;
        pv[q * 64 + lane] = v[q];
    }
}

// ---------------- Kernel 3: NF[t] = P[t] (1024x1024) * X_t (1024x128), fp32 ----------------
// 16x128 tile, 512 blocks (2/CU), 2x4 micro-tile, K-chunks of 32.
__global__ __launch_bounds__(256) void gemm2(const float* __restrict__ P,
                                             const float* __restrict__ X,
                                             float* __restrict__ NF) {
    const int t  = blockIdx.y;
    const int i0 = blockIdx.x * 16;
    const float* At = P + (size_t)t * N * N;
    const float* Xt = X + (size_t)t * N * D;

    __shared__ float Ps[16 * 36];
    __shared__ float Xs[32 * 132];

    const int tid = threadIdx.x;
    const int tx = tid & 31, ty = tid >> 5;     // tx: col group (0..31), ty: row pair (0..7)

    float4 acc0 = {0.f, 0.f, 0.f, 0.f};
    float4 acc1 = {0.f, 0.f, 0.f, 0.f};

    for (int kc = 0; kc < N; kc += 32) {
        if (tid < 128) {
            int r = tid >> 3, c4 = (tid & 7) * 4;
            *(float4*)(Ps + r * 36 + c4) = *(const float4*)(At + (size_t)(i0 + r) * N + kc + c4);
        }
        #pragma unroll
        for (int p = 0; p < 4; ++p) {
            int idx = tid + p * 256;            // 0..1023
            int r = idx >> 5, c4 = (idx & 31) * 4;
            *(float4*)(Xs + r * 132 + c4) = *(const float4*)(Xt + (size_t)(kc + r) * D + c4);
        }
        __syncthreads();
        #pragma unroll
        for (int k4 = 0; k4 < 8; ++k4) {
            float4 a0 = *(const float4*)(Ps + (ty * 2 + 0) * 36 + k4 * 4);
            float4 a1 = *(const float4*)(Ps + (ty * 2 + 1) * 36 + k4 * 4);
            const float a0v[4] = {a0.x, a0.y, a0.z, a0.w};
            const float a1v[4] = {a1.x, a1.y, a1.z, a1.w};
            #pragma unroll
            for (int j = 0; j < 4; ++j) {
                float4 x4 = *(const float4*)(Xs + (k4 * 4 + j) * 132 + tx * 4);
                acc0.x += a0v[j] * x4.x; acc0.y += a0v[j] * x4.y;
                acc0.z += a0v[j] * x4.z; acc0.w += a0v[j] * x4.w;
                acc1.x += a1v[j] * x4.x; acc1.y += a1v[j] * x4.y;
                acc1.z += a1v[j] * x4.z; acc1.w += a1v[j] * x4.w;
            }
        }
        __syncthreads();
    }

    float* NFt = NF + (size_t)t * N * D;
    *(float4*)(NFt + (size_t)(i0 + ty * 2 + 0) * D + tx * 4) = acc0;
    *(float4*)(NFt + (size_t)(i0 + ty * 2 + 1) * D + tx * 4) = acc1;
}

// ---------------- Kernel 4: SW[j,a,b] = sigmoid(scale * dot(NF[a,j,:], NF[b,j,:])) ----------------
__global__ __launch_bounds__(64) void temporal(const float* __restrict__ NF,
                                               float* __restrict__ SW) {
    const int j = blockIdx.x;
    __shared__ float F[T][D];
    const int tid = threadIdx.x;
    #pragma unroll
    for (int p = 0; p < 4; ++p) {
        int idx = tid + p * 64;                 // 0..255 float4 slots
        int a = idx >> 5, c4 = (idx & 31) * 4;
        *(float4*)(&F[a][c4]) = *(const float4*)(NF + ((size_t)a * N + j) * D + c4);
    }
    __syncthreads();
    const int a = tid >> 3, b = tid & 7;
    float s = 0.f;
    #pragma unroll
    for (int d4 = 0; d4 < 32; ++d4) {
        float4 fa = *(const float4*)(&F[a][d4 * 4]);
        float4 fb = *(const float4*)(&F[b][d4 * 4]);
        s += fa.x * fb.x + fa.y * fb.y + fa.z * fb.z + fa.w * fb.w;
    }
    s *= SCALE;
    SW[(size_t)j * 64 + tid] = 1.f / (1.f + __expf(-s));
}

// ---------------- Kernel 5: out[b*N+j, a*N+i] = SW[j,a,b] (broadcast over i) ----------------
__global__ __launch_bounds__(256) void expand(const float* __restrict__ SW,
                                              float* __restrict__ out) {
    const int row = blockIdx.x;                 // 0..8191 = b*N + j
    const int b = row >> 10, j = row & 1023;
    const int tid = threadIdx.x;
    float4* orow = (float4*)(out + (size_t)row * (T * N));
    #pragma unroll
    for (int a = 0; a < T; ++a) {
        float w = SW[(size_t)j * 64 + a * 8 + b];
        orow[a * 256 + tid] = make_float4(w, w, w, w);
    }
}

extern "C" void kernel_launch(void* const* d_in, const int* in_sizes, int n_in,
                              void* d_out, int out_size, void* d_ws, size_t ws_size,
                              hipStream_t stream) {
    const float* X   = (const float*)d_in[0];   // [T,N,D] fp32
    const int*   adj = (const int*)d_in[1];     // [N,N] int32
    float* out = (float*)d_out;                 // [T*N, T*N] fp32

    float* S   = (float*)d_ws;                  // T*N*N floats (33.5 MB)
    float* NF  = S + (size_t)T * N * N;         // T*N*D floats (4 MB)
    float* SW  = NF + (size_t)T * N * D;        // N*T*T floats (256 KB)
    ushort* XB = (ushort*)(SW + (size_t)N * T * T); // T*N*D bf16 (2 MB)

    convert_bf16<<<dim3(T * N * D / 4 / 256), 256, 0, stream>>>(X, XB);
    gemm1_mfma<<<dim3(512), 256, 0, stream>>>(XB, adj, S);
    softmax_rows<<<dim3(T * N / 4), 256, 0, stream>>>(S);
    gemm2<<<dim3(N / 16, T), 256, 0, stream>>>(S, X, NF);
    temporal<<<dim3(N), 64, 0, stream>>>(NF, SW);
    expand<<<dim3(T * N), 256, 0, stream>>>(SW, out);
}

// Round 3
// 340.957 us; speedup vs baseline: 1.3263x; 1.0863x over previous
//
#include <hip/hip_runtime.h>
#include <hip/hip_bf16.h>
#include <math.h>

#define T 8
#define N 1024
#define D 128

constexpr float SCALE = 0.08838834764831845f; // 1/sqrt(128)

typedef __attribute__((ext_vector_type(8))) short short8;   // 8 bf16 (4 VGPRs)
typedef __attribute__((ext_vector_type(4))) float floatx4;  // MFMA acc

#define MFMA16(a, b, c) __builtin_amdgcn_mfma_f32_16x16x32_bf16((a), (b), (c), 0, 0, 0)

// ---------------- Kernel 0: X fp32 -> XB[t][n][d] bf16 ; XBT hi/lo [t][d][n] bf16 ----------------
__global__ __launch_bounds__(256) void convert_bf16(const float* __restrict__ X,
                                                    ushort* __restrict__ XB,
                                                    ushort* __restrict__ XBT_hi,
                                                    ushort* __restrict__ XBT_lo) {
    int idx = blockIdx.x * 256 + threadIdx.x;      // float4 index over [T*N, D/4]
    float4 v = ((const float4*)X)[idx];
    int row = idx >> 5;                            // t*N + n
    int d0  = (idx & 31) * 4;
    int t = row >> 10, n = row & 1023;
    float vv[4] = {v.x, v.y, v.z, v.w};
    ushort4 o;
    ushort* op = (ushort*)&o;
    #pragma unroll
    for (int k = 0; k < 4; ++k) {
        __hip_bfloat16 h = __float2bfloat16(vv[k]);
        float hf = __bfloat162float(h);
        __hip_bfloat16 l = __float2bfloat16(vv[k] - hf);
        op[k] = *(ushort*)&h;
        size_t toff = ((size_t)t * D + d0 + k) * N + n;
        XBT_hi[toff] = *(ushort*)&h;
        XBT_lo[toff] = *(ushort*)&l;
    }
    ((ushort4*)XB)[idx] = o;
}

// ---------------- Kernel 1: fused GAT row-block ----------------
// Block = 16 rows of one timestamp. 4 waves; wave w owns score cols [256w,256w+256).
// Phase 1: scores via 16x16x32 bf16 MFMA (A,B frags straight from L2-resident XB).
// Phase 2: mask + in-register row softmax (shuffle over m-group, LDS cross-wave).
// Phase 3: P -> LDS as compensated bf16 (hi+lo), XOR-swizzled 16B blocks.
// Phase 4: NF = P*X via 3-term compensated MFMA against XBT hi/lo.
__global__ __launch_bounds__(256) void attn_fused(const ushort* __restrict__ XB,
                                                  const ushort* __restrict__ XBT_hi,
                                                  const ushort* __restrict__ XBT_lo,
                                                  const int* __restrict__ adj,
                                                  float* __restrict__ NF) {
    const int t  = blockIdx.y;
    const int i0 = blockIdx.x * 16;
    const int tid  = threadIdx.x;
    const int wid  = tid >> 6;
    const int lane = tid & 63;
    const int m    = lane & 15;
    const int quad = lane >> 4;
    const int jbase = wid * 256;

    __shared__ ushort Ph[16][1024];    // swizzled bf16 hi
    __shared__ ushort Plo[16][1024];   // swizzled bf16 lo
    float* red = (float*)&Ph[0][0];    // aliased: [0..63] rowmax, [64..127] rowsum

    const ushort* Xt = XB + (size_t)t * N * D;

    // A-fragments for this row tile (reused across all 16 col-tiles)
    short8 afrag[4];
    {
        const ushort* pa = Xt + (size_t)(i0 + m) * D + quad * 8;
        #pragma unroll
        for (int kq = 0; kq < 4; ++kq) afrag[kq] = *(const short8*)(pa + kq * 32);
    }

    floatx4 acc[16];
    #pragma unroll
    for (int c = 0; c < 16; ++c) acc[c] = (floatx4){0.f, 0.f, 0.f, 0.f};

    // ---- Phase 1: scores ----
    #pragma unroll
    for (int c = 0; c < 16; ++c) {
        const ushort* pb = Xt + (size_t)(jbase + 16 * c + m) * D + quad * 8;
        short8 b0 = *(const short8*)(pb);
        short8 b1 = *(const short8*)(pb + 32);
        short8 b2 = *(const short8*)(pb + 64);
        short8 b3 = *(const short8*)(pb + 96);
        acc[c] = MFMA16(afrag[0], b0, acc[c]);
        acc[c] = MFMA16(afrag[1], b1, acc[c]);
        acc[c] = MFMA16(afrag[2], b2, acc[c]);
        acc[c] = MFMA16(afrag[3], b3, acc[c]);
    }

    // ---- Phase 2: mask + scale, then row softmax ----
    #pragma unroll
    for (int q = 0; q < 4; ++q) {
        const int i = i0 + quad * 4 + q;
        const int* arow = adj + (size_t)i * N + jbase + m;
        #pragma unroll
        for (int c = 0; c < 16; ++c) {
            int a = arow[16 * c];
            acc[c][q] = (a != 0) ? acc[c][q] * SCALE : -1e12f;
        }
    }

    float mx[4], inv[4];
    #pragma unroll
    for (int q = 0; q < 4; ++q) {
        float v_ = acc[0][q];
        #pragma unroll
        for (int c = 1; c < 16; ++c) v_ = fmaxf(v_, acc[c][q]);
        v_ = fmaxf(v_, __shfl_xor(v_, 1));
        v_ = fmaxf(v_, __shfl_xor(v_, 2));
        v_ = fmaxf(v_, __shfl_xor(v_, 4));
        v_ = fmaxf(v_, __shfl_xor(v_, 8));
        mx[q] = v_;
    }
    if (m == 0) {
        #pragma unroll
        for (int q = 0; q < 4; ++q) red[wid * 16 + quad * 4 + q] = mx[q];
    }
    __syncthreads();
    #pragma unroll
    for (int q = 0; q < 4; ++q) {
        int r = quad * 4 + q;
        mx[q] = fmaxf(fmaxf(red[r], red[16 + r]), fmaxf(red[32 + r], red[48 + r]));
    }

    float sm[4];
    #pragma unroll
    for (int q = 0; q < 4; ++q) {
        float s_ = 0.f;
        #pragma unroll
        for (int c = 0; c < 16; ++c) {
            float p = __expf(acc[c][q] - mx[q]);
            acc[c][q] = p;
            s_ += p;
        }
        s_ += __shfl_xor(s_, 1);
        s_ += __shfl_xor(s_, 2);
        s_ += __shfl_xor(s_, 4);
        s_ += __shfl_xor(s_, 8);
        sm[q] = s_;
    }
    if (m == 0) {
        #pragma unroll
        for (int q = 0; q < 4; ++q) red[64 + wid * 16 + quad * 4 + q] = sm[q];
    }
    __syncthreads();
    #pragma unroll
    for (int q = 0; q < 4; ++q) {
        int r = quad * 4 + q;
        inv[q] = 1.f / (red[64 + r] + red[80 + r] + red[96 + r] + red[112 + r]);
    }
    __syncthreads();   // all red reads done before Ph overwrites the region

    // ---- Phase 3: P -> LDS (compensated bf16, XOR-swizzled 16B blocks) ----
    #pragma unroll
    for (int q = 0; q < 4; ++q) {
        const int row = quad * 4 + q;
        #pragma unroll
        for (int c = 0; c < 16; ++c) {
            const int col = jbase + 16 * c + m;
            const int sc = ((((col >> 3) ^ (row & 7)) << 3) | (col & 7));
            float p = acc[c][q] * inv[q];
            __hip_bfloat16 h = __float2bfloat16(p);
            float hf = __bfloat162float(h);
            __hip_bfloat16 l = __float2bfloat16(p - hf);
            Ph[row][sc]  = *(ushort*)&h;
            Plo[row][sc] = *(ushort*)&l;
        }
    }
    __syncthreads();

    // ---- Phase 4: NF = P * X  (3-term compensated bf16 MFMA) ----
    floatx4 accN[2];
    accN[0] = (floatx4){0.f, 0.f, 0.f, 0.f};
    accN[1] = (floatx4){0.f, 0.f, 0.f, 0.f};
    const int f0 = wid * 32;
    #pragma unroll 4
    for (int kq = 0; kq < 32; ++kq) {
        const int blk = (((kq * 4 + quad) ^ (m & 7)) << 3);
        short8 ah = *(const short8*)&Ph[m][blk];
        short8 al = *(const short8*)&Plo[m][blk];
        #pragma unroll
        for (int nt = 0; nt < 2; ++nt) {
            size_t off = ((size_t)t * D + f0 + nt * 16 + m) * N + kq * 32 + quad * 8;
            short8 bh = *(const short8*)(XBT_hi + off);
            short8 bl = *(const short8*)(XBT_lo + off);
            accN[nt] = MFMA16(ah, bh, accN[nt]);
            accN[nt] = MFMA16(ah, bl, accN[nt]);
            accN[nt] = MFMA16(al, bh, accN[nt]);
        }
    }

    float* NFt = NF + (size_t)t * N * D;
    #pragma unroll
    for (int nt = 0; nt < 2; ++nt)
        #pragma unroll
        for (int q = 0; q < 4; ++q)
            NFt[(size_t)(i0 + quad * 4 + q) * D + f0 + nt * 16 + m] = accN[nt][q];
}

// ---------------- Kernel 2: SW[j,a,b] = sigmoid(scale * dot(NF[a,j,:], NF[b,j,:])) ----------------
__global__ __launch_bounds__(64) void temporal(const float* __restrict__ NF,
                                               float* __restrict__ SW) {
    const int j = blockIdx.x;
    __shared__ float F[T][D];
    const int tid = threadIdx.x;
    #pragma unroll
    for (int p = 0; p < 4; ++p) {
        int idx = tid + p * 64;                 // 0..255 float4 slots
        int a = idx >> 5, c4 = (idx & 31) * 4;
        *(float4*)(&F[a][c4]) = *(const float4*)(NF + ((size_t)a * N + j) * D + c4);
    }
    __syncthreads();
    const int a = tid >> 3, b = tid & 7;
    float s = 0.f;
    #pragma unroll
    for (int d4 = 0; d4 < 32; ++d4) {
        float4 fa = *(const float4*)(&F[a][d4 * 4]);
        float4 fb = *(const float4*)(&F[b][d4 * 4]);
        s += fa.x * fb.x + fa.y * fb.y + fa.z * fb.z + fa.w * fb.w;
    }
    s *= SCALE;
    SW[(size_t)j * 64 + tid] = 1.f / (1.f + __expf(-s));
}

// ---------------- Kernel 3: out[b*N+j, a*N+i] = SW[j,a,b] (broadcast over i) ----------------
__global__ __launch_bounds__(256) void expand(const float* __restrict__ SW,
                                              float* __restrict__ out) {
    const int row = blockIdx.x;                 // 0..8191 = b*N + j
    const int b = row >> 10, j = row & 1023;
    const int tid = threadIdx.x;
    float4* orow = (float4*)(out + (size_t)row * (T * N));
    #pragma unroll
    for (int a = 0; a < T; ++a) {
        float w = SW[(size_t)j * 64 + a * 8 + b];
        orow[a * 256 + tid] = make_float4(w, w, w, w);
    }
}

extern "C" void kernel_launch(void* const* d_in, const int* in_sizes, int n_in,
                              void* d_out, int out_size, void* d_ws, size_t ws_size,
                              hipStream_t stream) {
    const float* X   = (const float*)d_in[0];   // [T,N,D] fp32
    const int*   adj = (const int*)d_in[1];     // [N,N] int32
    float* out = (float*)d_out;                 // [T*N, T*N] fp32

    float*  NF     = (float*)d_ws;                        // T*N*D fp32 (4 MB)
    float*  SW     = NF + (size_t)T * N * D;              // N*64 fp32 (256 KB)
    ushort* XB     = (ushort*)(SW + (size_t)N * T * T);   // T*N*D bf16 (2 MB)
    ushort* XBT_hi = XB + (size_t)T * N * D;              // T*D*N bf16 (2 MB)
    ushort* XBT_lo = XBT_hi + (size_t)T * N * D;          // T*D*N bf16 (2 MB)

    convert_bf16<<<dim3(T * N * D / 4 / 256), 256, 0, stream>>>(X, XB, XBT_hi, XBT_lo);
    attn_fused<<<dim3(N / 16, T), 256, 0, stream>>>(XB, XBT_hi, XBT_lo, adj, NF);
    temporal<<<dim3(N), 64, 0, stream>>>(NF, SW);
    expand<<<dim3(T * N), 256, 0, stream>>>(SW, out);
}

// Round 5
// 326.771 us; speedup vs baseline: 1.3839x; 1.0434x over previous
//
#include <hip/hip_runtime.h>
#include <hip/hip_bf16.h>
#include <math.h>

#define T 8
#define N 1024
#define D 128

constexpr float SCALE = 0.08838834764831845f; // 1/sqrt(128)

typedef __attribute__((ext_vector_type(8))) short short8;   // 8 bf16 (4 VGPRs)
typedef __attribute__((ext_vector_type(4))) float floatx4;  // MFMA acc / native float4

#define MFMA16(a, b, c) __builtin_amdgcn_mfma_f32_16x16x32_bf16((a), (b), (c), 0, 0, 0)

// ---------------- Kernel 0: X fp32 -> XB[t][n][d] bf16 ; XBT hi/lo [t][d][n] bf16 ----------------
__global__ __launch_bounds__(256) void convert_bf16(const float* __restrict__ X,
                                                    ushort* __restrict__ XB,
                                                    ushort* __restrict__ XBT_hi,
                                                    ushort* __restrict__ XBT_lo) {
    int idx = blockIdx.x * 256 + threadIdx.x;      // float4 index over [T*N, D/4]
    float4 v = ((const float4*)X)[idx];
    int row = idx >> 5;                            // t*N + n
    int d0  = (idx & 31) * 4;
    int t = row >> 10, n = row & 1023;
    float vv[4] = {v.x, v.y, v.z, v.w};
    ushort4 o;
    ushort* op = (ushort*)&o;
    #pragma unroll
    for (int k = 0; k < 4; ++k) {
        __hip_bfloat16 h = __float2bfloat16(vv[k]);
        float hf = __bfloat162float(h);
        __hip_bfloat16 l = __float2bfloat16(vv[k] - hf);
        op[k] = *(ushort*)&h;
        size_t toff = ((size_t)t * D + d0 + k) * N + n;
        XBT_hi[toff] = *(ushort*)&h;
        XBT_lo[toff] = *(ushort*)&l;
    }
    ((ushort4*)XB)[idx] = o;
}

// ---------------- Kernel 1: fused GAT row-block ----------------
// Block = 16 rows of one timestamp. 4 waves; wave w owns score cols [256w,256w+256).
// Phase 1: scores via 16x16x32 bf16 MFMA (A,B frags straight from L2-resident XB).
// Phase 2: mask + in-register row softmax (shuffle over m-group, LDS cross-wave).
// Phase 3: P -> LDS as compensated bf16 (hi+lo), XOR-swizzled 16B blocks.
// Phase 4: NF = P*X via 3-term compensated MFMA against XBT hi/lo.
__global__ __launch_bounds__(256) void attn_fused(const ushort* __restrict__ XB,
                                                  const ushort* __restrict__ XBT_hi,
                                                  const ushort* __restrict__ XBT_lo,
                                                  const int* __restrict__ adj,
                                                  float* __restrict__ NF) {
    const int t  = blockIdx.y;
    const int i0 = blockIdx.x * 16;
    const int tid  = threadIdx.x;
    const int wid  = tid >> 6;
    const int lane = tid & 63;
    const int m    = lane & 15;
    const int quad = lane >> 4;
    const int jbase = wid * 256;

    __shared__ ushort Ph[16][1024];    // swizzled bf16 hi
    __shared__ ushort Plo[16][1024];   // swizzled bf16 lo
    float* red = (float*)&Ph[0][0];    // aliased: [0..63] rowmax, [64..127] rowsum

    const ushort* Xt = XB + (size_t)t * N * D;

    // A-fragments for this row tile (reused across all 16 col-tiles)
    short8 afrag[4];
    {
        const ushort* pa = Xt + (size_t)(i0 + m) * D + quad * 8;
        #pragma unroll
        for (int kq = 0; kq < 4; ++kq) afrag[kq] = *(const short8*)(pa + kq * 32);
    }

    floatx4 acc[16];
    #pragma unroll
    for (int c = 0; c < 16; ++c) acc[c] = (floatx4){0.f, 0.f, 0.f, 0.f};

    // ---- Phase 1: scores ----
    #pragma unroll
    for (int c = 0; c < 16; ++c) {
        const ushort* pb = Xt + (size_t)(jbase + 16 * c + m) * D + quad * 8;
        short8 b0 = *(const short8*)(pb);
        short8 b1 = *(const short8*)(pb + 32);
        short8 b2 = *(const short8*)(pb + 64);
        short8 b3 = *(const short8*)(pb + 96);
        acc[c] = MFMA16(afrag[0], b0, acc[c]);
        acc[c] = MFMA16(afrag[1], b1, acc[c]);
        acc[c] = MFMA16(afrag[2], b2, acc[c]);
        acc[c] = MFMA16(afrag[3], b3, acc[c]);
    }

    // ---- Phase 2: mask + scale, then row softmax ----
    #pragma unroll
    for (int q = 0; q < 4; ++q) {
        const int i = i0 + quad * 4 + q;
        const int* arow = adj + (size_t)i * N + jbase + m;
        #pragma unroll
        for (int c = 0; c < 16; ++c) {
            int a = arow[16 * c];
            acc[c][q] = (a != 0) ? acc[c][q] * SCALE : -1e12f;
        }
    }

    float mx[4], inv[4];
    #pragma unroll
    for (int q = 0; q < 4; ++q) {
        float v_ = acc[0][q];
        #pragma unroll
        for (int c = 1; c < 16; ++c) v_ = fmaxf(v_, acc[c][q]);
        v_ = fmaxf(v_, __shfl_xor(v_, 1));
        v_ = fmaxf(v_, __shfl_xor(v_, 2));
        v_ = fmaxf(v_, __shfl_xor(v_, 4));
        v_ = fmaxf(v_, __shfl_xor(v_, 8));
        mx[q] = v_;
    }
    if (m == 0) {
        #pragma unroll
        for (int q = 0; q < 4; ++q) red[wid * 16 + quad * 4 + q] = mx[q];
    }
    __syncthreads();
    #pragma unroll
    for (int q = 0; q < 4; ++q) {
        int r = quad * 4 + q;
        mx[q] = fmaxf(fmaxf(red[r], red[16 + r]), fmaxf(red[32 + r], red[48 + r]));
    }

    float sm[4];
    #pragma unroll
    for (int q = 0; q < 4; ++q) {
        float s_ = 0.f;
        #pragma unroll
        for (int c = 0; c < 16; ++c) {
            float p = __expf(acc[c][q] - mx[q]);
            acc[c][q] = p;
            s_ += p;
        }
        s_ += __shfl_xor(s_, 1);
        s_ += __shfl_xor(s_, 2);
        s_ += __shfl_xor(s_, 4);
        s_ += __shfl_xor(s_, 8);
        sm[q] = s_;
    }
    if (m == 0) {
        #pragma unroll
        for (int q = 0; q < 4; ++q) red[64 + wid * 16 + quad * 4 + q] = sm[q];
    }
    __syncthreads();
    #pragma unroll
    for (int q = 0; q < 4; ++q) {
        int r = quad * 4 + q;
        inv[q] = 1.f / (red[64 + r] + red[80 + r] + red[96 + r] + red[112 + r]);
    }
    __syncthreads();   // all red reads done before Ph overwrites the region

    // ---- Phase 3: P -> LDS (compensated bf16, XOR-swizzled 16B blocks) ----
    #pragma unroll
    for (int q = 0; q < 4; ++q) {
        const int row = quad * 4 + q;
        #pragma unroll
        for (int c = 0; c < 16; ++c) {
            const int col = jbase + 16 * c + m;
            const int sc = ((((col >> 3) ^ (row & 7)) << 3) | (col & 7));
            float p = acc[c][q] * inv[q];
            __hip_bfloat16 h = __float2bfloat16(p);
            float hf = __bfloat162float(h);
            __hip_bfloat16 l = __float2bfloat16(p - hf);
            Ph[row][sc]  = *(ushort*)&h;
            Plo[row][sc] = *(ushort*)&l;
        }
    }
    __syncthreads();

    // ---- Phase 4: NF = P * X  (3-term compensated bf16 MFMA) ----
    floatx4 accN[2];
    accN[0] = (floatx4){0.f, 0.f, 0.f, 0.f};
    accN[1] = (floatx4){0.f, 0.f, 0.f, 0.f};
    const int f0 = wid * 32;
    #pragma unroll 4
    for (int kq = 0; kq < 32; ++kq) {
        const int blk = (((kq * 4 + quad) ^ (m & 7)) << 3);
        short8 ah = *(const short8*)&Ph[m][blk];
        short8 al = *(const short8*)&Plo[m][blk];
        #pragma unroll
        for (int nt = 0; nt < 2; ++nt) {
            size_t off = ((size_t)t * D + f0 + nt * 16 + m) * N + kq * 32 + quad * 8;
            short8 bh = *(const short8*)(XBT_hi + off);
            short8 bl = *(const short8*)(XBT_lo + off);
            accN[nt] = MFMA16(ah, bh, accN[nt]);
            accN[nt] = MFMA16(ah, bl, accN[nt]);
            accN[nt] = MFMA16(al, bh, accN[nt]);
        }
    }

    float* NFt = NF + (size_t)t * N * D;
    #pragma unroll
    for (int nt = 0; nt < 2; ++nt)
        #pragma unroll
        for (int q = 0; q < 4; ++q)
            NFt[(size_t)(i0 + quad * 4 + q) * D + f0 + nt * 16 + m] = accN[nt][q];
}

// ---------------- Kernel 2: fused temporal-gram + sigmoid + broadcast-expand ----------------
// Block = one output row (b*N + j). Stages NF[:,j,:] (4 KB), recomputes the 8
// sigmoid dots for (j, :, b), then streams the 32 KB row with nontemporal float4.
__global__ __launch_bounds__(256) void expand_fused(const float* __restrict__ NF,
                                                    float* __restrict__ out) {
    const int row = blockIdx.x;                 // 0..8191 = b*N + j
    const int b = row >> 10, j = row & 1023;
    const int tid = threadIdx.x;

    __shared__ float F[T][D + 4];               // +4 pad: lanes a=0..7 hit distinct banks
    __shared__ float w[T];

    {   // stage NF[a][j][:] — 256 threads x float4 = 4 KB
        int a = tid >> 5, c4 = (tid & 31) * 4;
        *(float4*)(&F[a][c4]) = *(const float4*)(NF + ((size_t)a * N + j) * D + c4);
    }
    __syncthreads();

    if (tid < T) {                              // 8 lanes: dot(F[tid], F[b])
        float s = 0.f;
        #pragma unroll
        for (int d4 = 0; d4 < 32; ++d4) {
            float4 fa = *(const float4*)(&F[tid][d4 * 4]);
            float4 fb = *(const float4*)(&F[b][d4 * 4]);
            s += fa.x * fb.x + fa.y * fb.y + fa.z * fb.z + fa.w * fb.w;
        }
        w[tid] = 1.f / (1.f + __expf(-s * SCALE));
    }
    __syncthreads();

    floatx4* orow = (floatx4*)(out + (size_t)row * (T * N));
    #pragma unroll
    for (int a = 0; a < T; ++a) {
        float wv = w[a];
        floatx4 v = {wv, wv, wv, wv};
        __builtin_nontemporal_store(v, orow + a * 256 + tid);
    }
}

extern "C" void kernel_launch(void* const* d_in, const int* in_sizes, int n_in,
                              void* d_out, int out_size, void* d_ws, size_t ws_size,
                              hipStream_t stream) {
    const float* X   = (const float*)d_in[0];   // [T,N,D] fp32
    const int*   adj = (const int*)d_in[1];     // [N,N] int32
    float* out = (float*)d_out;                 // [T*N, T*N] fp32

    float*  NF     = (float*)d_ws;                        // T*N*D fp32 (4 MB)
    ushort* XB     = (ushort*)(NF + (size_t)T * N * D);   // T*N*D bf16 (2 MB)
    ushort* XBT_hi = XB + (size_t)T * N * D;              // T*D*N bf16 (2 MB)
    ushort* XBT_lo = XBT_hi + (size_t)T * N * D;          // T*D*N bf16 (2 MB)

    convert_bf16<<<dim3(T * N * D / 4 / 256), 256, 0, stream>>>(X, XB, XBT_hi, XBT_lo);
    attn_fused<<<dim3(N / 16, T), 256, 0, stream>>>(XB, XBT_hi, XBT_lo, adj, NF);
    expand_fused<<<dim3(T * N), 256, 0, stream>>>(NF, out);
}